// Round 10
// baseline (141.810 us; speedup 1.0000x reference)
//
#include <hip/hip_runtime.h>
#include <hip/hip_bf16.h>

typedef unsigned short u16;
typedef __attribute__((ext_vector_type(8))) short short8;
typedef __attribute__((ext_vector_type(4))) float f32x4;

#define H 8
#define N 384
#define D 32
#define CIN 256
#define HNN (H * N * N)
#define SCALER 0.17677669529663687f
#define EPS 1e-9f

// workspace float offsets
#define PROJ_OFF 0u              // 5*H*N*D = 491520: a,b,c,vj,vk as [5][H][N][D]
#define S_OFF    491520u         // 3*H*N*N: t=0 XT[k][j], t=1 YT[i][k], t=2 Z[i][j]
#define VJT_OFF  4030464u        // H*D*N = 98304: vj transposed [h][d][n]
#define VKT_OFF  4128768u        // H*D*N
#define MX_OFF   4227072u        // 8
#define MY_OFF   4227080u        // H*N
#define MZ_OFF   4230152u        // H*N
#define NUM_OFF  4233224u        // H*N*D
#define DEN_OFF  4331528u        // H*N
#define XBF_OFF  4334600u        // ushort[H*N*N] = 589824 float slots (XT bf16)
#define ZBF_OFF  4924424u        // ushort[H*N*N] (Z bf16)
#define MXROW_OFF 5514248u       // H*N row maxima of X plane

__device__ inline float bf2f(u16 u) {
    union { unsigned int x; float f; } c; c.x = ((unsigned int)u) << 16; return c.f;
}
__device__ inline u16 f2bf(float f) {
    unsigned int x = __float_as_uint(f);
    return (u16)((x + 0x7FFFu + ((x >> 16) & 1u)) >> 16);
}

// ---------------- K1: projection GEMM  wx[n,m] = sum_k hs[n,k]*W[m,k] ----------------
__global__ __launch_bounds__(256) void proj_kernel(const float* __restrict__ hs,
                                                   const float* __restrict__ W,
                                                   float* __restrict__ proj,
                                                   float* __restrict__ projT) {
    __shared__ float hs_s[64][68];
    __shared__ float w_s[64][68];
    const int tid = threadIdx.x;
    const int tx = tid & 15, ty = tid >> 4;
    const int m0 = blockIdx.x * 64, n0 = blockIdx.y * 64;
    float acc[4][4] = {};
    for (int k0 = 0; k0 < CIN; k0 += 64) {
        __syncthreads();
#pragma unroll
        for (int rep = 0; rep < 4; ++rep) {
            int lin = rep * 1024 + tid * 4;
            int rl = lin >> 6, kl = lin & 63;
            float4 hv = *(const float4*)&hs[(n0 + rl) * CIN + k0 + kl];
            hs_s[kl + 0][rl] = hv.x; hs_s[kl + 1][rl] = hv.y;
            hs_s[kl + 2][rl] = hv.z; hs_s[kl + 3][rl] = hv.w;
            float4 wv = *(const float4*)&W[(m0 + rl) * CIN + k0 + kl];
            w_s[kl + 0][rl] = wv.x; w_s[kl + 1][rl] = wv.y;
            w_s[kl + 2][rl] = wv.z; w_s[kl + 3][rl] = wv.w;
        }
        __syncthreads();
#pragma unroll 16
        for (int kk = 0; kk < 64; ++kk) {
            float4 a4 = *(const float4*)&hs_s[kk][ty * 4];
            float4 b4 = *(const float4*)&w_s[kk][tx * 4];
            float av[4] = {a4.x, a4.y, a4.z, a4.w};
            float bv[4] = {b4.x, b4.y, b4.z, b4.w};
#pragma unroll
            for (int a_ = 0; a_ < 4; ++a_) {
#pragma unroll
                for (int b_ = 0; b_ < 4; ++b_) {
                    acc[a_][b_] = fmaf(av[a_], bv[b_], acc[a_][b_]);
                }
            }
        }
    }
#pragma unroll
    for (int a_ = 0; a_ < 4; ++a_) {
        int n = n0 + ty * 4 + a_;
#pragma unroll
        for (int b_ = 0; b_ < 4; ++b_) {
            int m = m0 + tx * 4 + b_;
            int s = m >> 8, hh = (m >> 5) & 7, d = m & 31;
            proj[s * (H * N * D) + hh * (N * D) + n * D + d] = acc[a_][b_];
            if (s >= 3) projT[(s - 3) * (H * D * N) + hh * (D * N) + d * N + n] = acc[a_][b_];
        }
    }
}

// ---------------- K2: scores ----------------
// t=0: XT[k,j] = c_k . b_j ; t=1: YT[i,k] = a_i . c_k ; t=2: Z[i,j] = a_i . b_j
// one 64x64 tile per block
__global__ __launch_bounds__(256) void scores_kernel(const float* __restrict__ proj,
                                                     float* __restrict__ S) {
    __shared__ float LsT[32][68];
    __shared__ float RsT[32][68];
    const int tid = threadIdx.x, tx = tid & 15, ty = tid >> 4;
    const int rt = blockIdx.x % 6, ct = blockIdx.x / 6;
    const int r0 = rt * 64, c0 = ct * 64;
    const int h = blockIdx.y;
    const int t = blockIdx.z;
    const int Lidx = (t == 0) ? 2 : 0;
    const int Ridx = (t == 1) ? 2 : 1;
    const float* Lp = proj + Lidx * (H * N * D) + h * (N * D);
    const float* Rp = proj + Ridx * (H * N * D) + h * (N * D);
    float* Sp = S + t * HNN + h * (N * N);
    {
        int i = tid >> 2, d8 = (tid & 3) * 8;
        float4 v0 = *(const float4*)&Lp[(r0 + i) * D + d8];
        float4 v1 = *(const float4*)&Lp[(r0 + i) * D + d8 + 4];
        LsT[d8 + 0][i] = v0.x; LsT[d8 + 1][i] = v0.y; LsT[d8 + 2][i] = v0.z; LsT[d8 + 3][i] = v0.w;
        LsT[d8 + 4][i] = v1.x; LsT[d8 + 5][i] = v1.y; LsT[d8 + 6][i] = v1.z; LsT[d8 + 7][i] = v1.w;
        float4 w0 = *(const float4*)&Rp[(c0 + i) * D + d8];
        float4 w1 = *(const float4*)&Rp[(c0 + i) * D + d8 + 4];
        RsT[d8 + 0][i] = w0.x; RsT[d8 + 1][i] = w0.y; RsT[d8 + 2][i] = w0.z; RsT[d8 + 3][i] = w0.w;
        RsT[d8 + 4][i] = w1.x; RsT[d8 + 5][i] = w1.y; RsT[d8 + 6][i] = w1.z; RsT[d8 + 7][i] = w1.w;
    }
    __syncthreads();
    float acc[4][4] = {};
#pragma unroll
    for (int dd = 0; dd < 32; ++dd) {
        float4 l4 = *(const float4*)&LsT[dd][ty * 4];
        float4 r4 = *(const float4*)&RsT[dd][tx * 4];
        float lv[4] = {l4.x, l4.y, l4.z, l4.w};
        float rv[4] = {r4.x, r4.y, r4.z, r4.w};
#pragma unroll
        for (int a_ = 0; a_ < 4; ++a_) {
#pragma unroll
            for (int b_ = 0; b_ < 4; ++b_) {
                acc[a_][b_] = fmaf(lv[a_], rv[b_], acc[a_][b_]);
            }
        }
    }
#pragma unroll
    for (int a_ = 0; a_ < 4; ++a_) {
        float4 o;
        o.x = acc[a_][0] * SCALER; o.y = acc[a_][1] * SCALER;
        o.z = acc[a_][2] * SCALER; o.w = acc[a_][3] * SCALER;
        *(float4*)&Sp[(r0 + ty * 4 + a_) * N + c0 + tx * 4] = o;
    }
}

// ---------------- K3: row maxima for all three planes ----------------
__global__ void rowmax_kernel(const float* __restrict__ S, float* __restrict__ mXrow,
                              float* __restrict__ mY, float* __restrict__ mZ) {
    const int z = blockIdx.z;
    const int h = blockIdx.y;
    const int r = blockIdx.x * 4 + (threadIdx.x >> 6);
    const int lane = threadIdx.x & 63;
    const float* row = S + z * HNN + h * (N * N) + r * N;
    float m = -3.0e38f;
    for (int q = lane; q < N; q += 64) m = fmaxf(m, row[q]);
#pragma unroll
    for (int off = 32; off; off >>= 1) m = fmaxf(m, __shfl_down(m, off));
    if (lane == 0) (z == 0 ? mXrow : (z == 1 ? mY : mZ))[h * N + r] = m;
}

// reduce mXrow[h][0..N) -> mX[h]; grid 8 x 64 threads
__global__ void reduce_mx_kernel(const float* __restrict__ mXrow, float* __restrict__ mX) {
    const int h = blockIdx.x;
    const int lane = threadIdx.x;
    float m = -3.0e38f;
    for (int q = lane; q < N; q += 64) m = fmaxf(m, mXrow[h * N + q]);
#pragma unroll
    for (int off = 32; off; off >>= 1) m = fmaxf(m, __shfl_down(m, off));
    if (lane == 0) mX[h] = m;
}

// ---------------- K4: exp.  t=1 writes f32 in place; t=0/2 write bf16 copies ----------------
__global__ void exp_kernel(float* __restrict__ S, const float* __restrict__ mX,
                           const float* __restrict__ mY, const float* __restrict__ mZ,
                           u16* __restrict__ Xbf, u16* __restrict__ Zbf) {
    int f8 = blockIdx.x * 256 + threadIdx.x;  // 442368 total
    int flat = f8 * 8;
    int t = flat / HNN;
    int rem = flat - t * HNN;
    int h = rem / (N * N);
    int rc = rem - h * (N * N);
    int r = rc / N;
    float m = (t == 0) ? mX[h] : ((t == 1) ? mY[h * N + r] : mZ[h * N + r]);
    float4 v0 = *(float4*)&S[flat];
    float4 v1 = *(float4*)&S[flat + 4];
    float e[8] = {__expf(v0.x - m), __expf(v0.y - m), __expf(v0.z - m), __expf(v0.w - m),
                  __expf(v1.x - m), __expf(v1.y - m), __expf(v1.z - m), __expf(v1.w - m)};
    if (t == 1) {
        float4 o0 = {e[0], e[1], e[2], e[3]}, o1 = {e[4], e[5], e[6], e[7]};
        *(float4*)&S[flat] = o0;
        *(float4*)&S[flat + 4] = o1;
    } else {
        short8 ov;
#pragma unroll
        for (int q = 0; q < 8; ++q) ov[q] = (short)f2bf(e[q]);
        u16* dst = (t == 0 ? Xbf : Zbf) + h * (N * N) + rc;
        *(short8*)dst = ov;
    }
}

// ---------------- K5: cubic contraction via MFMA bf16, v8 (fi=2/fk=4: half LDS per MFMA) ----------------
// block = (h, i-tile of 64, d-group of 2). 768 thr = 12 waves = 2 i-groups x 6 k-groups.
// Wave (ig,kg) owns rows ig*32..+31, k in [kg*64, kg*64+64). Per js: 4 A LDS reads +
// 4 B global loads + 16 MFMAs -> 64 FLOP/LDS-byte (2x round 9) -> MFMA-pipe bound.
// LDS: two A tiles (Z .* vj_d0/d1) 96 KB + red 3 KB -> 1 block/CU, 12 waves (3/SIMD).
// Regs ~140 <= 170 cap (768,3) -> no spill (tripwire: WRITE_SIZE).
__global__ __launch_bounds__(768, 3) void cubic_mfma(
        const u16* __restrict__ Xbf, const u16* __restrict__ Zbf,
        const float* __restrict__ Yt, const float* __restrict__ vjT,
        const float* __restrict__ vkT, float* __restrict__ NumB,
        float* __restrict__ DenB) {
    const int orig = blockIdx.x;             // 0..815 (816 = 8 x 102, bijective)
    const int wg = (orig & 7) * 102 + (orig >> 3);
    const int h   = wg / 102;                // one head per XCD
    const int rem = wg - h * 102;
    const int dg  = rem / 6;                 // 0..16
    const int it6 = rem - dg * 6;            // 0..5
    const int i0  = it6 * 64;
    const bool dgden = (dg == 16);
    const int d0 = dgden ? 0 : 2 * dg;
    const int d1 = dgden ? 0 : 2 * dg + 1;
    const int tid = threadIdx.x;
    const int w = tid >> 6, lane = tid & 63;
    __shared__ u16 A_lds[2 * 64 * N];        // [t][i][j], chunk-swizzled: jchunk ^= (i&7)
    __shared__ float red[2][6][64];
    u16* A0 = A_lds;
    u16* A1 = A_lds + 64 * N;
    const u16* Zh = Zbf + h * (N * N);
    const u16* Xh = Xbf + h * (N * N);
    const float* Yth = Yt + h * (N * N);
    const float* vjd0 = vjT + h * (D * N) + d0 * N;
    const float* vjd1 = vjT + h * (D * N) + d1 * N;
    const float* vkd0 = vkT + h * (D * N) + d0 * N;
    const float* vkd1 = vkT + h * (D * N) + d1 * N;

    // ---- A-prep: 64 rows x 48 chunks(short8) x 2 tiles; wave w covers chunks [w*4,w*4+4)
    {
        const int row = lane;                // each wave's 64 lanes = 64 rows
        const u16* zrow = &Zh[(i0 + row) * N];
        const int swp = (row & 7) << 3;
        u16* a0row = &A0[row * N];
        u16* a1row = &A1[row * N];
#pragma unroll
        for (int q = 0; q < 4; ++q) {
            const int jb = (w * 4 + q) * 8;
            short8 zv = *(const short8*)&zrow[jb];
            short8 o0, o1;
            if (dgden) {
                o0 = zv; o1 = zv;
            } else {
                float4 p0 = *(const float4*)&vjd0[jb];
                float4 p1 = *(const float4*)&vjd0[jb + 4];
                float4 q0 = *(const float4*)&vjd1[jb];
                float4 q1 = *(const float4*)&vjd1[jb + 4];
                float v0[8] = {p0.x, p0.y, p0.z, p0.w, p1.x, p1.y, p1.z, p1.w};
                float v1[8] = {q0.x, q0.y, q0.z, q0.w, q1.x, q1.y, q1.z, q1.w};
#pragma unroll
                for (int e = 0; e < 8; ++e) {
                    float zf = bf2f((u16)zv[e]);
                    o0[e] = (short)f2bf(zf * v0[e]);
                    o1[e] = (short)f2bf(zf * v1[e]);
                }
            }
            *(short8*)&a0row[jb ^ swp] = o0;
            *(short8*)&a1row[jb ^ swp] = o1;
        }
    }
    __syncthreads();

    // ---- MFMA main loop: no barriers, k held in accumulators; B ping-pong prefetch
    f32x4 acc0[2][4], acc1[2][4];
#pragma unroll
    for (int fi = 0; fi < 2; ++fi)
#pragma unroll
        for (int fk = 0; fk < 4; ++fk) {
            acc0[fi][fk] = (f32x4){0.f, 0.f, 0.f, 0.f};
            acc1[fi][fk] = (f32x4){0.f, 0.f, 0.f, 0.f};
        }

    const int ig = w / 6;             // 0..1 (i-group)
    const int kg = w % 6;             // 0..5 (k-group)
    const int l15 = lane & 15;
    const int jc = (lane >> 4) * 8;
    const int sw = (l15 & 7) << 3;    // ig*32 + fi*16 keeps row&7 == l15&7
    const int kwb = kg * 64 + l15;
    const int arow0 = ig * 32 + l15;  // fi=0 row; fi=1 adds 16
    const u16* Br0 = &Xh[(kwb +  0) * N];
    const u16* Br1 = &Xh[(kwb + 16) * N];
    const u16* Br2 = &Xh[(kwb + 32) * N];
    const u16* Br3 = &Xh[(kwb + 48) * N];

    short8 bA[4], bB[4];
    bA[0] = *(const short8*)&Br0[jc];
    bA[1] = *(const short8*)&Br1[jc];
    bA[2] = *(const short8*)&Br2[jc];
    bA[3] = *(const short8*)&Br3[jc];

#pragma unroll
    for (int it = 0; it < 6; ++it) {
        const int js0 = it * 2, js1 = it * 2 + 1;
        {   // prefetch js1
            const int j = js1 * 32 + jc;
            bB[0] = *(const short8*)&Br0[j];
            bB[1] = *(const short8*)&Br1[j];
            bB[2] = *(const short8*)&Br2[j];
            bB[3] = *(const short8*)&Br3[j];
        }
        {   // compute js0 with bA
            const int j = js0 * 32 + jc;
            short8 a0[2], a1[2];
#pragma unroll
            for (int fi = 0; fi < 2; ++fi) {
                a0[fi] = *(const short8*)&A0[(arow0 + fi * 16) * N + (j ^ sw)];
                a1[fi] = *(const short8*)&A1[(arow0 + fi * 16) * N + (j ^ sw)];
            }
#pragma unroll
            for (int fk = 0; fk < 4; ++fk) {
#pragma unroll
                for (int fi = 0; fi < 2; ++fi) {
                    acc0[fi][fk] = __builtin_amdgcn_mfma_f32_16x16x32_bf16(a0[fi], bA[fk], acc0[fi][fk], 0, 0, 0);
                    acc1[fi][fk] = __builtin_amdgcn_mfma_f32_16x16x32_bf16(a1[fi], bA[fk], acc1[fi][fk], 0, 0, 0);
                }
            }
        }
        if (it < 5) {   // prefetch next js0
            const int j = (js1 + 1) * 32 + jc;
            bA[0] = *(const short8*)&Br0[j];
            bA[1] = *(const short8*)&Br1[j];
            bA[2] = *(const short8*)&Br2[j];
            bA[3] = *(const short8*)&Br3[j];
        }
        {   // compute js1 with bB
            const int j = js1 * 32 + jc;
            short8 a0[2], a1[2];
#pragma unroll
            for (int fi = 0; fi < 2; ++fi) {
                a0[fi] = *(const short8*)&A0[(arow0 + fi * 16) * N + (j ^ sw)];
                a1[fi] = *(const short8*)&A1[(arow0 + fi * 16) * N + (j ^ sw)];
            }
#pragma unroll
            for (int fk = 0; fk < 4; ++fk) {
#pragma unroll
                for (int fi = 0; fi < 2; ++fi) {
                    acc0[fi][fk] = __builtin_amdgcn_mfma_f32_16x16x32_bf16(a0[fi], bB[fk], acc0[fi][fk], 0, 0, 0);
                    acc1[fi][fk] = __builtin_amdgcn_mfma_f32_16x16x32_bf16(a1[fi], bB[fk], acc1[fi][fk], 0, 0, 0);
                }
            }
        }
    }

    // ---- epilogue: weight by YT[i,k]*vk[k,d], reduce over k; d0 then d1 (caps reg peak)
    const int rbase = (lane >> 4) << 2;
    {   // d0
        float np[2][4];
#pragma unroll
        for (int fi = 0; fi < 2; ++fi)
#pragma unroll
            for (int reg = 0; reg < 4; ++reg) np[fi][reg] = 0.f;
#pragma unroll
        for (int fk = 0; fk < 4; ++fk) {
            const int kcol = kwb + fk * 16;
            const float vkv = dgden ? 1.0f : vkd0[kcol];
#pragma unroll
            for (int fi = 0; fi < 2; ++fi) {
#pragma unroll
                for (int reg = 0; reg < 4; ++reg) {
                    const int irow = i0 + ig * 32 + fi * 16 + rbase + reg;
                    const float wgt = Yth[irow * N + kcol] * vkv;
                    np[fi][reg] = fmaf(acc0[fi][fk][reg], wgt, np[fi][reg]);
                }
            }
        }
#pragma unroll
        for (int fi = 0; fi < 2; ++fi) {
#pragma unroll
            for (int reg = 0; reg < 4; ++reg) {
                float v = np[fi][reg];
                v += __shfl_xor(v, 1); v += __shfl_xor(v, 2);
                v += __shfl_xor(v, 4); v += __shfl_xor(v, 8);
                np[fi][reg] = v;
            }
        }
        if (l15 == 0) {
#pragma unroll
            for (int fi = 0; fi < 2; ++fi)
#pragma unroll
                for (int reg = 0; reg < 4; ++reg)
                    red[0][kg][ig * 32 + fi * 16 + rbase + reg] = np[fi][reg];
        }
    }
    {   // d1
        float np[2][4];
#pragma unroll
        for (int fi = 0; fi < 2; ++fi)
#pragma unroll
            for (int reg = 0; reg < 4; ++reg) np[fi][reg] = 0.f;
#pragma unroll
        for (int fk = 0; fk < 4; ++fk) {
            const int kcol = kwb + fk * 16;
            const float vkv = dgden ? 1.0f : vkd1[kcol];
#pragma unroll
            for (int fi = 0; fi < 2; ++fi) {
#pragma unroll
                for (int reg = 0; reg < 4; ++reg) {
                    const int irow = i0 + ig * 32 + fi * 16 + rbase + reg;
                    const float wgt = Yth[irow * N + kcol] * vkv;
                    np[fi][reg] = fmaf(acc1[fi][fk][reg], wgt, np[fi][reg]);
                }
            }
        }
#pragma unroll
        for (int fi = 0; fi < 2; ++fi) {
#pragma unroll
            for (int reg = 0; reg < 4; ++reg) {
                float v = np[fi][reg];
                v += __shfl_xor(v, 1); v += __shfl_xor(v, 2);
                v += __shfl_xor(v, 4); v += __shfl_xor(v, 8);
                np[fi][reg] = v;
            }
        }
        if (l15 == 0) {
#pragma unroll
            for (int fi = 0; fi < 2; ++fi)
#pragma unroll
                for (int reg = 0; reg < 4; ++reg)
                    red[1][kg][ig * 32 + fi * 16 + rbase + reg] = np[fi][reg];
        }
    }
    __syncthreads();
    if (tid < 64) {
        float s = 0.f;
#pragma unroll
        for (int qq = 0; qq < 6; ++qq) s += red[0][qq][tid];
        if (!dgden) NumB[h * (N * D) + (i0 + tid) * D + 2 * dg] = s;
        else        DenB[h * N + i0 + tid] = s;
    } else if (tid < 128 && !dgden) {
        const int i = tid - 64;
        float s = 0.f;
#pragma unroll
        for (int qq = 0; qq < 6; ++qq) s += red[1][qq][i];
        NumB[h * (N * D) + (i0 + i) * D + 2 * dg + 1] = s;
    }
}

// ---------------- K6: normalize + fp32 output [n, h*D+d] ----------------
__global__ void out_kernel(const float* __restrict__ NumB, const float* __restrict__ DenB,
                           float* __restrict__ out) {
    int idx = blockIdx.x * 256 + threadIdx.x;  // 0..98303
    int n = idx >> 8;
    int ch = idx & 255;
    int hh = ch >> 5, d = ch & 31;
    float v = NumB[hh * (N * D) + n * D + d] / (DenB[hh * N + n] + EPS);
    out[idx] = v;
}

extern "C" void kernel_launch(void* const* d_in, const int* in_sizes, int n_in,
                              void* d_out, int out_size, void* d_ws, size_t ws_size,
                              hipStream_t stream) {
    const float* hs = (const float*)d_in[0];
    const float* W  = (const float*)d_in[1];
    float* ws = (float*)d_ws;
    float* proj  = ws + PROJ_OFF;
    float* S     = ws + S_OFF;
    float* projT = ws + VJT_OFF;    // vj rows, then vk rows at +H*D*N
    float* mX    = ws + MX_OFF;
    float* mY    = ws + MY_OFF;
    float* mZ    = ws + MZ_OFF;
    float* NumB  = ws + NUM_OFF;
    float* DenB  = ws + DEN_OFF;
    u16*   Xbf   = (u16*)(ws + XBF_OFF);
    u16*   Zbf   = (u16*)(ws + ZBF_OFF);
    float* mXrow = ws + MXROW_OFF;
    float* out = (float*)d_out;

    proj_kernel<<<dim3(20, 6), 256, 0, stream>>>(hs, W, proj, projT);
    scores_kernel<<<dim3(36, 8, 3), 256, 0, stream>>>(proj, S);
    rowmax_kernel<<<dim3(96, 8, 3), 256, 0, stream>>>(S, mXrow, mY, mZ);
    reduce_mx_kernel<<<8, 64, 0, stream>>>(mXrow, mX);
    exp_kernel<<<1728, 256, 0, stream>>>(S, mX, mY, mZ, Xbf, Zbf);
    cubic_mfma<<<dim3(816), 768, 0, stream>>>(Xbf, Zbf, S + HNN, ws + VJT_OFF,
                                              ws + VKT_OFF, NumB, DenB);
    out_kernel<<<(H * N * D) / 256, 256, 0, stream>>>(NumB, DenB, out);
}

// Round 11
// 117.686 us; speedup vs baseline: 1.2050x; 1.2050x over previous
//
#include <hip/hip_runtime.h>
#include <hip/hip_bf16.h>

typedef unsigned short u16;
typedef __attribute__((ext_vector_type(8))) short short8;
typedef __attribute__((ext_vector_type(4))) float f32x4;

#define H 8
#define N 384
#define D 32
#define CIN 256
#define HNN (H * N * N)
#define SCALER 0.17677669529663687f
#define EPS 1e-9f

// workspace float offsets
#define PROJ_OFF 0u              // 5*H*N*D = 491520: a,b,c,vj,vk as [5][H][N][D]
#define S_OFF    491520u         // 3*H*N*N: t=0 XT[k][j], t=1 YT[i][k], t=2 Z[i][j]
#define VJT_OFF  4030464u        // H*D*N = 98304: vj transposed [h][d][n]
#define VKT_OFF  4128768u        // H*D*N
#define MX_OFF   4227072u        // 8
#define MY_OFF   4227080u        // H*N
#define MZ_OFF   4230152u        // H*N
#define NUM_OFF  4233224u        // H*N*D
#define DEN_OFF  4331528u        // H*N
#define XBF_OFF  4334600u        // ushort[H*N*N] = 589824 float slots (XT bf16)
#define ZBF_OFF  4924424u        // ushort[H*N*N] (Z bf16)
#define MXROW_OFF 5514248u       // H*N row maxima of X plane

__device__ inline float bf2f(u16 u) {
    union { unsigned int x; float f; } c; c.x = ((unsigned int)u) << 16; return c.f;
}
__device__ inline u16 f2bf(float f) {
    unsigned int x = __float_as_uint(f);
    return (u16)((x + 0x7FFFu + ((x >> 16) & 1u)) >> 16);
}

// ---------------- K1: projection GEMM  wx[n,m] = sum_k hs[n,k]*W[m,k] ----------------
__global__ __launch_bounds__(256) void proj_kernel(const float* __restrict__ hs,
                                                   const float* __restrict__ W,
                                                   float* __restrict__ proj,
                                                   float* __restrict__ projT) {
    __shared__ float hs_s[64][68];
    __shared__ float w_s[64][68];
    const int tid = threadIdx.x;
    const int tx = tid & 15, ty = tid >> 4;
    const int m0 = blockIdx.x * 64, n0 = blockIdx.y * 64;
    float acc[4][4] = {};
    for (int k0 = 0; k0 < CIN; k0 += 64) {
        __syncthreads();
#pragma unroll
        for (int rep = 0; rep < 4; ++rep) {
            int lin = rep * 1024 + tid * 4;
            int rl = lin >> 6, kl = lin & 63;
            float4 hv = *(const float4*)&hs[(n0 + rl) * CIN + k0 + kl];
            hs_s[kl + 0][rl] = hv.x; hs_s[kl + 1][rl] = hv.y;
            hs_s[kl + 2][rl] = hv.z; hs_s[kl + 3][rl] = hv.w;
            float4 wv = *(const float4*)&W[(m0 + rl) * CIN + k0 + kl];
            w_s[kl + 0][rl] = wv.x; w_s[kl + 1][rl] = wv.y;
            w_s[kl + 2][rl] = wv.z; w_s[kl + 3][rl] = wv.w;
        }
        __syncthreads();
#pragma unroll 16
        for (int kk = 0; kk < 64; ++kk) {
            float4 a4 = *(const float4*)&hs_s[kk][ty * 4];
            float4 b4 = *(const float4*)&w_s[kk][tx * 4];
            float av[4] = {a4.x, a4.y, a4.z, a4.w};
            float bv[4] = {b4.x, b4.y, b4.z, b4.w};
#pragma unroll
            for (int a_ = 0; a_ < 4; ++a_) {
#pragma unroll
                for (int b_ = 0; b_ < 4; ++b_) {
                    acc[a_][b_] = fmaf(av[a_], bv[b_], acc[a_][b_]);
                }
            }
        }
    }
#pragma unroll
    for (int a_ = 0; a_ < 4; ++a_) {
        int n = n0 + ty * 4 + a_;
#pragma unroll
        for (int b_ = 0; b_ < 4; ++b_) {
            int m = m0 + tx * 4 + b_;
            int s = m >> 8, hh = (m >> 5) & 7, d = m & 31;
            proj[s * (H * N * D) + hh * (N * D) + n * D + d] = acc[a_][b_];
            if (s >= 3) projT[(s - 3) * (H * D * N) + hh * (D * N) + d * N + n] = acc[a_][b_];
        }
    }
}

// ---------------- K2: scores ----------------
// t=0: XT[k,j] = c_k . b_j ; t=1: YT[i,k] = a_i . c_k ; t=2: Z[i,j] = a_i . b_j
// one 64x64 tile per block
__global__ __launch_bounds__(256) void scores_kernel(const float* __restrict__ proj,
                                                     float* __restrict__ S) {
    __shared__ float LsT[32][68];
    __shared__ float RsT[32][68];
    const int tid = threadIdx.x, tx = tid & 15, ty = tid >> 4;
    const int rt = blockIdx.x % 6, ct = blockIdx.x / 6;
    const int r0 = rt * 64, c0 = ct * 64;
    const int h = blockIdx.y;
    const int t = blockIdx.z;
    const int Lidx = (t == 0) ? 2 : 0;
    const int Ridx = (t == 1) ? 2 : 1;
    const float* Lp = proj + Lidx * (H * N * D) + h * (N * D);
    const float* Rp = proj + Ridx * (H * N * D) + h * (N * D);
    float* Sp = S + t * HNN + h * (N * N);
    {
        int i = tid >> 2, d8 = (tid & 3) * 8;
        float4 v0 = *(const float4*)&Lp[(r0 + i) * D + d8];
        float4 v1 = *(const float4*)&Lp[(r0 + i) * D + d8 + 4];
        LsT[d8 + 0][i] = v0.x; LsT[d8 + 1][i] = v0.y; LsT[d8 + 2][i] = v0.z; LsT[d8 + 3][i] = v0.w;
        LsT[d8 + 4][i] = v1.x; LsT[d8 + 5][i] = v1.y; LsT[d8 + 6][i] = v1.z; LsT[d8 + 7][i] = v1.w;
        float4 w0 = *(const float4*)&Rp[(c0 + i) * D + d8];
        float4 w1 = *(const float4*)&Rp[(c0 + i) * D + d8 + 4];
        RsT[d8 + 0][i] = w0.x; RsT[d8 + 1][i] = w0.y; RsT[d8 + 2][i] = w0.z; RsT[d8 + 3][i] = w0.w;
        RsT[d8 + 4][i] = w1.x; RsT[d8 + 5][i] = w1.y; RsT[d8 + 6][i] = w1.z; RsT[d8 + 7][i] = w1.w;
    }
    __syncthreads();
    float acc[4][4] = {};
#pragma unroll
    for (int dd = 0; dd < 32; ++dd) {
        float4 l4 = *(const float4*)&LsT[dd][ty * 4];
        float4 r4 = *(const float4*)&RsT[dd][tx * 4];
        float lv[4] = {l4.x, l4.y, l4.z, l4.w};
        float rv[4] = {r4.x, r4.y, r4.z, r4.w};
#pragma unroll
        for (int a_ = 0; a_ < 4; ++a_) {
#pragma unroll
            for (int b_ = 0; b_ < 4; ++b_) {
                acc[a_][b_] = fmaf(lv[a_], rv[b_], acc[a_][b_]);
            }
        }
    }
#pragma unroll
    for (int a_ = 0; a_ < 4; ++a_) {
        float4 o;
        o.x = acc[a_][0] * SCALER; o.y = acc[a_][1] * SCALER;
        o.z = acc[a_][2] * SCALER; o.w = acc[a_][3] * SCALER;
        *(float4*)&Sp[(r0 + ty * 4 + a_) * N + c0 + tx * 4] = o;
    }
}

// ---------------- K3: row maxima for all three planes ----------------
__global__ void rowmax_kernel(const float* __restrict__ S, float* __restrict__ mXrow,
                              float* __restrict__ mY, float* __restrict__ mZ) {
    const int z = blockIdx.z;
    const int h = blockIdx.y;
    const int r = blockIdx.x * 4 + (threadIdx.x >> 6);
    const int lane = threadIdx.x & 63;
    const float* row = S + z * HNN + h * (N * N) + r * N;
    float m = -3.0e38f;
    for (int q = lane; q < N; q += 64) m = fmaxf(m, row[q]);
#pragma unroll
    for (int off = 32; off; off >>= 1) m = fmaxf(m, __shfl_down(m, off));
    if (lane == 0) (z == 0 ? mXrow : (z == 1 ? mY : mZ))[h * N + r] = m;
}

// reduce mXrow[h][0..N) -> mX[h]; grid 8 x 64 threads
__global__ void reduce_mx_kernel(const float* __restrict__ mXrow, float* __restrict__ mX) {
    const int h = blockIdx.x;
    const int lane = threadIdx.x;
    float m = -3.0e38f;
    for (int q = lane; q < N; q += 64) m = fmaxf(m, mXrow[h * N + q]);
#pragma unroll
    for (int off = 32; off; off >>= 1) m = fmaxf(m, __shfl_down(m, off));
    if (lane == 0) mX[h] = m;
}

// ---------------- K4: exp.  t=1 writes f32 in place; t=0/2 write bf16 copies ----------------
__global__ void exp_kernel(float* __restrict__ S, const float* __restrict__ mX,
                           const float* __restrict__ mY, const float* __restrict__ mZ,
                           u16* __restrict__ Xbf, u16* __restrict__ Zbf) {
    int f8 = blockIdx.x * 256 + threadIdx.x;  // 442368 total
    int flat = f8 * 8;
    int t = flat / HNN;
    int rem = flat - t * HNN;
    int h = rem / (N * N);
    int rc = rem - h * (N * N);
    int r = rc / N;
    float m = (t == 0) ? mX[h] : ((t == 1) ? mY[h * N + r] : mZ[h * N + r]);
    float4 v0 = *(float4*)&S[flat];
    float4 v1 = *(float4*)&S[flat + 4];
    float e[8] = {__expf(v0.x - m), __expf(v0.y - m), __expf(v0.z - m), __expf(v0.w - m),
                  __expf(v1.x - m), __expf(v1.y - m), __expf(v1.z - m), __expf(v1.w - m)};
    if (t == 1) {
        float4 o0 = {e[0], e[1], e[2], e[3]}, o1 = {e[4], e[5], e[6], e[7]};
        *(float4*)&S[flat] = o0;
        *(float4*)&S[flat + 4] = o1;
    } else {
        short8 ov;
#pragma unroll
        for (int q = 0; q < 8; ++q) ov[q] = (short)f2bf(e[q]);
        u16* dst = (t == 0 ? Xbf : Zbf) + h * (N * N) + rc;
        *(short8*)dst = ov;
    }
}

// ---------------- K5: cubic contraction via MFMA bf16, v9 (r9 geometry + coalesced A-prep) ----------------
// block = (h, i-tile of 64, d-group of 2). 768 thr = 12 waves, wave owns 32 k.
// Per js: 8 A LDS reads + 2 B global loads + 16 MFMAs (min global-loads/MFMA — r10 lesson).
// A-prep linearized: consecutive tids read contiguous Z (coalesced) and write consecutive
// swizzled LDS chunks (<=2-way banks) — fixes r9's 8-way prep-write conflicts + scattered Z reads.
// LDS: two A tiles 96 KB + red 6 KB -> 1 block/CU, 12 waves (3/SIMD).
__global__ __launch_bounds__(768, 3) void cubic_mfma(
        const u16* __restrict__ Xbf, const u16* __restrict__ Zbf,
        const float* __restrict__ Yt, const float* __restrict__ vjT,
        const float* __restrict__ vkT, float* __restrict__ NumB,
        float* __restrict__ DenB) {
    const int orig = blockIdx.x;             // 0..815 (816 = 8 x 102, bijective)
    const int wg = (orig & 7) * 102 + (orig >> 3);
    const int h   = wg / 102;                // one head per XCD
    const int rem = wg - h * 102;
    const int dg  = rem / 6;                 // 0..16
    const int it6 = rem - dg * 6;            // 0..5
    const int i0  = it6 * 64;
    const bool dgden = (dg == 16);
    const int d0 = dgden ? 0 : 2 * dg;
    const int d1 = dgden ? 0 : 2 * dg + 1;
    const int tid = threadIdx.x;
    const int w = tid >> 6, lane = tid & 63;
    __shared__ u16 A_lds[2 * 64 * N];        // [t][i][j], chunk-swizzled: jchunk ^= (i&7)
    __shared__ float red[2][12][64];
    u16* A0 = A_lds;
    u16* A1 = A_lds + 64 * N;
    const u16* Zh = Zbf + h * (N * N);
    const u16* Xh = Xbf + h * (N * N);
    const float* Yth = Yt + h * (N * N);
    const float* vjd0 = vjT + h * (D * N) + d0 * N;
    const float* vjd1 = vjT + h * (D * N) + d1 * N;
    const float* vkd0 = vkT + h * (D * N) + d0 * N;
    const float* vkd1 = vkT + h * (D * N) + d1 * N;

    // ---- A-prep (coalesced): 3072 chunks(short8); 4 iters x 768 thr; writes both tiles
    {
#pragma unroll
        for (int it = 0; it < 4; ++it) {
            const int g = it * 768 + tid;        // 0..3071
            const int row = g / 48;
            const int cb = g - row * 48;
            const int jb = cb * 8;
            const int dst = row * N + (jb ^ ((row & 7) << 3));
            short8 zv = *(const short8*)&Zh[(i0 + row) * N + jb];
            if (dgden) {
                *(short8*)&A0[dst] = zv;
                *(short8*)&A1[dst] = zv;
            } else {
                float4 p0 = *(const float4*)&vjd0[jb];
                float4 p1 = *(const float4*)&vjd0[jb + 4];
                float4 q0 = *(const float4*)&vjd1[jb];
                float4 q1 = *(const float4*)&vjd1[jb + 4];
                float v0[8] = {p0.x, p0.y, p0.z, p0.w, p1.x, p1.y, p1.z, p1.w};
                float v1[8] = {q0.x, q0.y, q0.z, q0.w, q1.x, q1.y, q1.z, q1.w};
                short8 o0, o1;
#pragma unroll
                for (int e = 0; e < 8; ++e) {
                    float zf = bf2f((u16)zv[e]);
                    o0[e] = (short)f2bf(zf * v0[e]);
                    o1[e] = (short)f2bf(zf * v1[e]);
                }
                *(short8*)&A0[dst] = o0;
                *(short8*)&A1[dst] = o1;
            }
        }
    }
    __syncthreads();

    // ---- MFMA main loop: no barriers, k held in accumulators; B ping-pong prefetch
    f32x4 acc0[4][2], acc1[4][2];
#pragma unroll
    for (int fi = 0; fi < 4; ++fi)
#pragma unroll
        for (int fk = 0; fk < 2; ++fk) {
            acc0[fi][fk] = (f32x4){0.f, 0.f, 0.f, 0.f};
            acc1[fi][fk] = (f32x4){0.f, 0.f, 0.f, 0.f};
        }

    const int l15 = lane & 15;
    const int jc = (lane >> 4) * 8;
    const int sw = (l15 & 7) << 3;    // fi*16 keeps row&7 == lane&7
    const int kwb = w * 32 + l15;
    const u16* Br0 = &Xh[(kwb +  0) * N];
    const u16* Br1 = &Xh[(kwb + 16) * N];

    short8 bA[2], bB[2];
    bA[0] = *(const short8*)&Br0[jc];
    bA[1] = *(const short8*)&Br1[jc];

#pragma unroll
    for (int it = 0; it < 6; ++it) {
        const int js0 = it * 2, js1 = it * 2 + 1;
        {   // prefetch js1
            const int j = js1 * 32 + jc;
            bB[0] = *(const short8*)&Br0[j];
            bB[1] = *(const short8*)&Br1[j];
        }
        {   // compute js0 with bA
            const int j = js0 * 32 + jc;
            short8 a0[4], a1[4];
#pragma unroll
            for (int fi = 0; fi < 4; ++fi) {
                a0[fi] = *(const short8*)&A0[(fi * 16 + l15) * N + (j ^ sw)];
                a1[fi] = *(const short8*)&A1[(fi * 16 + l15) * N + (j ^ sw)];
            }
#pragma unroll
            for (int fk = 0; fk < 2; ++fk) {
#pragma unroll
                for (int fi = 0; fi < 4; ++fi) {
                    acc0[fi][fk] = __builtin_amdgcn_mfma_f32_16x16x32_bf16(a0[fi], bA[fk], acc0[fi][fk], 0, 0, 0);
                    acc1[fi][fk] = __builtin_amdgcn_mfma_f32_16x16x32_bf16(a1[fi], bA[fk], acc1[fi][fk], 0, 0, 0);
                }
            }
        }
        if (it < 5) {   // prefetch next js0
            const int j = (js1 + 1) * 32 + jc;
            bA[0] = *(const short8*)&Br0[j];
            bA[1] = *(const short8*)&Br1[j];
        }
        {   // compute js1 with bB
            const int j = js1 * 32 + jc;
            short8 a0[4], a1[4];
#pragma unroll
            for (int fi = 0; fi < 4; ++fi) {
                a0[fi] = *(const short8*)&A0[(fi * 16 + l15) * N + (j ^ sw)];
                a1[fi] = *(const short8*)&A1[(fi * 16 + l15) * N + (j ^ sw)];
            }
#pragma unroll
            for (int fk = 0; fk < 2; ++fk) {
#pragma unroll
                for (int fi = 0; fi < 4; ++fi) {
                    acc0[fi][fk] = __builtin_amdgcn_mfma_f32_16x16x32_bf16(a0[fi], bB[fk], acc0[fi][fk], 0, 0, 0);
                    acc1[fi][fk] = __builtin_amdgcn_mfma_f32_16x16x32_bf16(a1[fi], bB[fk], acc1[fi][fk], 0, 0, 0);
                }
            }
        }
    }

    // ---- epilogue: weight by YT[i,k]*vk[k,d], reduce over k; d0 then d1 (caps reg peak)
    const int rbase = (lane >> 4) << 2;
    {   // d0
        float np[4][4];
#pragma unroll
        for (int fi = 0; fi < 4; ++fi)
#pragma unroll
            for (int reg = 0; reg < 4; ++reg) np[fi][reg] = 0.f;
#pragma unroll
        for (int fk = 0; fk < 2; ++fk) {
            const int kcol = kwb + fk * 16;
            const float vkv = dgden ? 1.0f : vkd0[kcol];
#pragma unroll
            for (int fi = 0; fi < 4; ++fi) {
#pragma unroll
                for (int reg = 0; reg < 4; ++reg) {
                    const int irow = i0 + fi * 16 + rbase + reg;
                    const float wgt = Yth[irow * N + kcol] * vkv;
                    np[fi][reg] = fmaf(acc0[fi][fk][reg], wgt, np[fi][reg]);
                }
            }
        }
#pragma unroll
        for (int fi = 0; fi < 4; ++fi) {
#pragma unroll
            for (int reg = 0; reg < 4; ++reg) {
                float v = np[fi][reg];
                v += __shfl_xor(v, 1); v += __shfl_xor(v, 2);
                v += __shfl_xor(v, 4); v += __shfl_xor(v, 8);
                np[fi][reg] = v;
            }
        }
        if (l15 == 0) {
#pragma unroll
            for (int fi = 0; fi < 4; ++fi)
#pragma unroll
                for (int reg = 0; reg < 4; ++reg)
                    red[0][w][fi * 16 + rbase + reg] = np[fi][reg];
        }
    }
    {   // d1
        float np[4][4];
#pragma unroll
        for (int fi = 0; fi < 4; ++fi)
#pragma unroll
            for (int reg = 0; reg < 4; ++reg) np[fi][reg] = 0.f;
#pragma unroll
        for (int fk = 0; fk < 2; ++fk) {
            const int kcol = kwb + fk * 16;
            const float vkv = dgden ? 1.0f : vkd1[kcol];
#pragma unroll
            for (int fi = 0; fi < 4; ++fi) {
#pragma unroll
                for (int reg = 0; reg < 4; ++reg) {
                    const int irow = i0 + fi * 16 + rbase + reg;
                    const float wgt = Yth[irow * N + kcol] * vkv;
                    np[fi][reg] = fmaf(acc1[fi][fk][reg], wgt, np[fi][reg]);
                }
            }
        }
#pragma unroll
        for (int fi = 0; fi < 4; ++fi) {
#pragma unroll
            for (int reg = 0; reg < 4; ++reg) {
                float v = np[fi][reg];
                v += __shfl_xor(v, 1); v += __shfl_xor(v, 2);
                v += __shfl_xor(v, 4); v += __shfl_xor(v, 8);
                np[fi][reg] = v;
            }
        }
        if (l15 == 0) {
#pragma unroll
            for (int fi = 0; fi < 4; ++fi)
#pragma unroll
                for (int reg = 0; reg < 4; ++reg)
                    red[1][w][fi * 16 + rbase + reg] = np[fi][reg];
        }
    }
    __syncthreads();
    if (tid < 64) {
        float s = 0.f;
#pragma unroll
        for (int ww = 0; ww < 12; ++ww) s += red[0][ww][tid];
        if (!dgden) NumB[h * (N * D) + (i0 + tid) * D + 2 * dg] = s;
        else        DenB[h * N + i0 + tid] = s;
    } else if (tid < 128 && !dgden) {
        const int i = tid - 64;
        float s = 0.f;
#pragma unroll
        for (int ww = 0; ww < 12; ++ww) s += red[1][ww][i];
        NumB[h * (N * D) + (i0 + i) * D + 2 * dg + 1] = s;
    }
}

// ---------------- K6: normalize + fp32 output [n, h*D+d] ----------------
__global__ void out_kernel(const float* __restrict__ NumB, const float* __restrict__ DenB,
                           float* __restrict__ out) {
    int idx = blockIdx.x * 256 + threadIdx.x;  // 0..98303
    int n = idx >> 8;
    int ch = idx & 255;
    int hh = ch >> 5, d = ch & 31;
    float v = NumB[hh * (N * D) + n * D + d] / (DenB[hh * N + n] + EPS);
    out[idx] = v;
}

extern "C" void kernel_launch(void* const* d_in, const int* in_sizes, int n_in,
                              void* d_out, int out_size, void* d_ws, size_t ws_size,
                              hipStream_t stream) {
    const float* hs = (const float*)d_in[0];
    const float* W  = (const float*)d_in[1];
    float* ws = (float*)d_ws;
    float* proj  = ws + PROJ_OFF;
    float* S     = ws + S_OFF;
    float* projT = ws + VJT_OFF;    // vj rows, then vk rows at +H*D*N
    float* mX    = ws + MX_OFF;
    float* mY    = ws + MY_OFF;
    float* mZ    = ws + MZ_OFF;
    float* NumB  = ws + NUM_OFF;
    float* DenB  = ws + DEN_OFF;
    u16*   Xbf   = (u16*)(ws + XBF_OFF);
    u16*   Zbf   = (u16*)(ws + ZBF_OFF);
    float* mXrow = ws + MXROW_OFF;
    float* out = (float*)d_out;

    proj_kernel<<<dim3(20, 6), 256, 0, stream>>>(hs, W, proj, projT);
    scores_kernel<<<dim3(36, 8, 3), 256, 0, stream>>>(proj, S);
    rowmax_kernel<<<dim3(96, 8, 3), 256, 0, stream>>>(S, mXrow, mY, mZ);
    reduce_mx_kernel<<<8, 64, 0, stream>>>(mXrow, mX);
    exp_kernel<<<1728, 256, 0, stream>>>(S, mX, mY, mZ, Xbf, Zbf);
    cubic_mfma<<<dim3(816), 768, 0, stream>>>(Xbf, Zbf, S + HNN, ws + VJT_OFF,
                                              ws + VKT_OFF, NumB, DenB);
    out_kernel<<<(H * N * D) / 256, 256, 0, stream>>>(NumB, DenB, out);
}